// Round 7
// baseline (857.428 us; speedup 1.0000x reference)
//
#include <hip/hip_runtime.h>

// PRNNLayer: B=4096 chains x T=2048 steps, 5 states.
// R9: R8 (one role per block, SoA planes + tx, no barriers) + TWO CHAINS PER
// THREAD. Role-1 is latency/trans-issue bound at 387 cyc/step with a single
// serial chain per lane and one wave per SIMD: ~90-175 cyc trans issue +
// ~70 VALU + ~150-200 cyc exposed dependent-chain stall. A second independent
// chain per lane fills the bubbles (the recurrence is non-associative, so
// cross-timestep parallelism is impossible; cross-chain ILP is free).
// 128 blocks x 64 threads: role = blockIdx.x & 3, group = blockIdx.x >> 2,
// chains b0 = group*128+lane and b1 = b0+64. CHUNK 16->8 to keep VGPRs sane.
// All state-update arithmetic verbatim from the verified R5-R8 kernels.

#define NB 4096
#define NT 2048
#define CHUNK 8
#define NCHUNK (NT / CHUNK)  // 256
#define BT ((size_t)NB * (size_t)NT)

#define L2E10 14.4269504089f  // 10*log2(e)  (hv(x) = sigmoid(10x))
#define L2E    1.44269504089f

__device__ __forceinline__ float rcpf(float x) { return __builtin_amdgcn_rcpf(x); }
__device__ __forceinline__ float ex2(float a)  { return __builtin_amdgcn_exp2f(a); }
__device__ __forceinline__ float ex2c(float a) { return __builtin_amdgcn_exp2f(fminf(a, 80.0f)); }
__device__ __forceinline__ float clip1e5(float x) {
    return __builtin_amdgcn_fmed3f(x, -100000.0f, 100000.0f);
}

__global__ __launch_bounds__(64, 1)
void prnn_roles(const float* __restrict__ inp, const float* __restrict__ theta,
                float* __restrict__ out, float* __restrict__ wsp, int use_ws) {
    const int lane = threadIdx.x;
    const int role = blockIdx.x & 3;
    const int b0 = (blockIdx.x >> 2) * 128 + lane;
    const int b1 = b0 + 64;

    // ---- theta (uniform); each role uses a subset, rest DCE'd ----
    const float f_     = theta[0] * 0.1f;
    const float smax_  = theta[1] * 1950.0f;
    const float qmax_  = theta[2] * 50.0f;
    const float ddf_   = theta[3] * 5.0f;
    const float tmin_  = theta[4] * -3.0f;
    const float tmax_  = theta[5] * 3.0f;
    const float Kc_    = theta[6] * 0.5f;
    const float SCmax_ = theta[7] * 1.5f;
    const float spmax_ = theta[8] * 1950.0f;
    const float qpmax_ = theta[9] * 40.0f;
    const float kp     = theta[10];
    const float sgmax_ = theta[11] * 1950.0f;
    const float qgmax_ = theta[12] * 40.0f;
    const float Kl_    = theta[13] * 0.5f;
    const float Kn_    = theta[14] * 0.5f;

    const float inv_smax = rcpf(smax_);
    const float KcDc  = Kc_ * 0.849932f;          // Kc_ * 0.986*0.862
    const float c_sn  = -L2E10 * tmin_;
    const float c_m   =  L2E10 * tmax_;
    const float c_dd  = -ddf_ * tmax_;
    const float c_sc1 =  L2E10 * SCmax_ * 1.4f;
    const float c_sc0 =  L2E10 * SCmax_ * 0.6f;
    const float c_2p  =  L2E10 * spmax_;
    const float c_3s  =  L2E10 * smax_;
    const float c_4s  =  L2E10 * sgmax_;
    const float fE    = f_ * L2E;
    const float c_E2  = -fE * spmax_;
    const float c_E3  = -fE * smax_;
    const float c_E4  = -fE * sgmax_;

    const float* ip0 = inp + (size_t)b0 * (NT * 3);
    const float* ip1 = inp + (size_t)b1 * (NT * 3);
    float*       op0 = out + (size_t)b0 * (NT * 5);
    float*       op1 = out + (size_t)b1 * (NT * 5);
    float* wbase = use_ws ? wsp : out;   // avoid null arith when no ws

    // 32B (CHUNK=8) plane store; the two halves of each 64B line come from
    // the same lane on consecutive chunks -> merge in L2.
    auto plane_store = [&](float* plane, const float* ob, int c) {
        float4* d = (float4*)(plane + (size_t)c * CHUNK);
        const float4* s = (const float4*)ob;
        #pragma unroll
        for (int i = 0; i < CHUNK / 4; ++i) d[i] = s[i];
    };

    if (role == 0) {
        // ---- s0: e0, esc, Rp = 3 trans/step/chain ----
        float sA = 0.f, sB = 0.f;
        float a0[CHUNK * 3], a1[CHUNK * 3], q0[CHUNK * 3], q1[CHUNK * 3];
        float* w0a = wbase + 0 * BT + (size_t)b0 * NT;
        float* w0b = wbase + 0 * BT + (size_t)b1 * NT;
        auto pf = [&](float* d0, float* d1, int c) {
            const float4* s0 = (const float4*)(ip0 + (size_t)c * (CHUNK * 3));
            const float4* s1 = (const float4*)(ip1 + (size_t)c * (CHUNK * 3));
            #pragma unroll
            for (int i = 0; i < (CHUNK * 3) / 4; ++i) {
                ((float4*)d0)[i] = s0[i];
                ((float4*)d1)[i] = s1[i];
            }
        };
        auto cw = [&](const float* d0, const float* d1, int c) {
            float ob0[CHUNK], ob1[CHUNK];
            #pragma unroll
            for (int i = 0; i < CHUNK; ++i) {
                {   // chain A
                    const float p  = d0[i * 3 + 0];
                    const float dl = d0[i * 3 + 2];
                    const float day = rcpf(1.0f + ex2(fmaf(-L2E10, dl, 7.21347520f)));
                    const float da  = 1.0f + ex2(fmaf(-L2E10, p, L2E));
                    const float lai   = fmaf(0.328f, day, 0.15f);
                    const float kcf   = fmaf(0.6f, day, 0.4f);
                    const float kterm = KcDc * kcf * lai;
                    const float zday  = fmaf(c_sc1, day, c_sc0);
                    const float e0  = ex2(-L2E10 * sA);
                    const float esc = ex2(fmaf(-L2E10, sA, zday));
                    const float d0_ = 1.0f + e0;
                    const float dsc = 1.0f + esc;
                    const float Rp  = rcpf(da * d0_ * dsc);
                    const float pintc = Rp * fmaf(d0_ * esc, kterm, p);
                    sA += clip1e5(pintc);
                    ob0[i] = sA;
                }
                {   // chain B
                    const float p  = d1[i * 3 + 0];
                    const float dl = d1[i * 3 + 2];
                    const float day = rcpf(1.0f + ex2(fmaf(-L2E10, dl, 7.21347520f)));
                    const float da  = 1.0f + ex2(fmaf(-L2E10, p, L2E));
                    const float lai   = fmaf(0.328f, day, 0.15f);
                    const float kcf   = fmaf(0.6f, day, 0.4f);
                    const float kterm = KcDc * kcf * lai;
                    const float zday  = fmaf(c_sc1, day, c_sc0);
                    const float e0  = ex2(-L2E10 * sB);
                    const float esc = ex2(fmaf(-L2E10, sB, zday));
                    const float d0_ = 1.0f + e0;
                    const float dsc = 1.0f + esc;
                    const float Rp  = rcpf(da * d0_ * dsc);
                    const float pintc = Rp * fmaf(d0_ * esc, kterm, p);
                    sB += clip1e5(pintc);
                    ob1[i] = sB;
                }
            }
            if (use_ws) { plane_store(w0a, ob0, c); plane_store(w0b, ob1, c); }
            else {
                #pragma unroll
                for (int i = 0; i < CHUNK; ++i) {
                    op0[(c * CHUNK + i) * 5 + 0] = ob0[i];
                    op1[(c * CHUNK + i) * 5 + 0] = ob1[i];
                }
            }
        };
        pf(a0, a1, 0);
        for (int c = 0; c < NCHUNK; c += 2) {
            pf(q0, q1, c + 1);
            cw(a0, a1, c);
            if (c + 2 < NCHUNK) pf(a0, a1, c + 2);
            cw(q0, q1, c + 1);
        }
    } else if (role == 1) {
        // ---- s1 + s3 (critical role): 11 trans/step/chain ----
        float s1A = 0.f, s3A = 0.f, s1B = 0.f, s3B = 0.f;
        float a0[CHUNK * 3], a1[CHUNK * 3], q0[CHUNK * 3], q1[CHUNK * 3];
        float* w1a = wbase + 1 * BT + (size_t)b0 * NT;
        float* w1b = wbase + 1 * BT + (size_t)b1 * NT;
        float* w3a = wbase + 3 * BT + (size_t)b0 * NT;
        float* w3b = wbase + 3 * BT + (size_t)b1 * NT;
        auto pf = [&](float* d0, float* d1, int c) {
            const float4* s0 = (const float4*)(ip0 + (size_t)c * (CHUNK * 3));
            const float4* s1 = (const float4*)(ip1 + (size_t)c * (CHUNK * 3));
            #pragma unroll
            for (int i = 0; i < (CHUNK * 3) / 4; ++i) {
                ((float4*)d0)[i] = s0[i];
                ((float4*)d1)[i] = s1[i];
            }
        };
        auto cw = [&](const float* d0, const float* d1, int c) {
            float ob1a[CHUNK], ob3a[CHUNK], ob1b[CHUNK], ob3b[CHUNK];
            #pragma unroll
            for (int i = 0; i < CHUNK; ++i) {
                {   // chain A
                    const float p  = d0[i * 3 + 0];
                    const float tm = d0[i * 3 + 1];
                    const float dl = d0[i * 3 + 2];
                    const float A1 = tm + 237.3f;
                    const float A2 = tm + 273.2f;
                    const float qq = rcpf(A1 * A2);
                    const float pe = 436.98672f * dl * ex2(24.958624f * tm * (qq * A2)) * (qq * A1);
                    const float psnow = rcpf(1.0f + ex2(fmaf(L2E10, tm, c_sn))) * p;
                    const float dm = 1.0f + ex2(fmaf(-L2E10, tm, c_m));
                    const float prain = p - psnow;
                    const float e1 = ex2(-L2E10 * s1A);
                    const float melt = rcpf(dm * (1.0f + e1))
                                       * fminf(s1A, fmaf(ddf_, tm, c_dd));
                    const float e3  = ex2(-L2E10 * s3A);
                    const float e3s = ex2c(fmaf(-L2E10, s3A, c_3s));
                    const float R3  = rcpf((1.0f + e3) * (1.0f + e3s));
                    const float E3  = ex2(fmaf(fE, s3A, c_E3));
                    const float t_et = pe * fmaf(e3s * s3A, inv_smax, 1.0f);
                    const float t_qs = qmax_ * fmaf(e3s, E3, 1.0f);
                    const float outflux = R3 * (t_et + t_qs + (s3A - smax_));
                    const float ds3 = prain + melt - outflux;
                    s1A += clip1e5(psnow - melt);
                    s3A += clip1e5(ds3);
                    ob1a[i] = s1A;
                    ob3a[i] = s3A;
                }
                {   // chain B
                    const float p  = d1[i * 3 + 0];
                    const float tm = d1[i * 3 + 1];
                    const float dl = d1[i * 3 + 2];
                    const float A1 = tm + 237.3f;
                    const float A2 = tm + 273.2f;
                    const float qq = rcpf(A1 * A2);
                    const float pe = 436.98672f * dl * ex2(24.958624f * tm * (qq * A2)) * (qq * A1);
                    const float psnow = rcpf(1.0f + ex2(fmaf(L2E10, tm, c_sn))) * p;
                    const float dm = 1.0f + ex2(fmaf(-L2E10, tm, c_m));
                    const float prain = p - psnow;
                    const float e1 = ex2(-L2E10 * s1B);
                    const float melt = rcpf(dm * (1.0f + e1))
                                       * fminf(s1B, fmaf(ddf_, tm, c_dd));
                    const float e3  = ex2(-L2E10 * s3B);
                    const float e3s = ex2c(fmaf(-L2E10, s3B, c_3s));
                    const float R3  = rcpf((1.0f + e3) * (1.0f + e3s));
                    const float E3  = ex2(fmaf(fE, s3B, c_E3));
                    const float t_et = pe * fmaf(e3s * s3B, inv_smax, 1.0f);
                    const float t_qs = qmax_ * fmaf(e3s, E3, 1.0f);
                    const float outflux = R3 * (t_et + t_qs + (s3B - smax_));
                    const float ds3 = prain + melt - outflux;
                    s1B += clip1e5(psnow - melt);
                    s3B += clip1e5(ds3);
                    ob1b[i] = s1B;
                    ob3b[i] = s3B;
                }
            }
            if (use_ws) {
                plane_store(w1a, ob1a, c); plane_store(w3a, ob3a, c);
                plane_store(w1b, ob1b, c); plane_store(w3b, ob3b, c);
            } else {
                #pragma unroll
                for (int i = 0; i < CHUNK; ++i) {
                    op0[(c * CHUNK + i) * 5 + 1] = ob1a[i];
                    op0[(c * CHUNK + i) * 5 + 3] = ob3a[i];
                    op1[(c * CHUNK + i) * 5 + 1] = ob1b[i];
                    op1[(c * CHUNK + i) * 5 + 3] = ob3b[i];
                }
            }
        };
        pf(a0, a1, 0);
        for (int c = 0; c < NCHUNK; c += 2) {
            pf(q0, q1, c + 1);
            cw(a0, a1, c);
            if (c + 2 < NCHUNK) pf(a0, a1, c + 2);
            cw(q0, q1, c + 1);
        }
    } else if (role == 2) {
        // ---- s2: 4 trans/step/chain ----
        float sA = 0.f, sB = 0.f;
        float a0[CHUNK], a1[CHUNK], q0[CHUNK], q1[CHUNK];
        float* w2a = wbase + 2 * BT + (size_t)b0 * NT;
        float* w2b = wbase + 2 * BT + (size_t)b1 * NT;
        auto pf = [&](float* P0, float* P1, int c) {
            #pragma unroll
            for (int i = 0; i < CHUNK; ++i) {
                P0[i] = ip0[(c * CHUNK + i) * 3 + 0];
                P1[i] = ip1[(c * CHUNK + i) * 3 + 0];
            }
        };
        auto cw = [&](const float* P0, const float* P1, int c) {
            float ob0[CHUNK], ob1[CHUNK];
            #pragma unroll
            for (int i = 0; i < CHUNK; ++i) {
                {
                    const float p = P0[i];
                    const float e2  = ex2(-L2E10 * sA);
                    const float e2p = ex2c(fmaf(-L2E10, sA, c_2p));
                    const float R2  = rcpf((1.0f + e2) * (1.0f + e2p));
                    const float E2  = ex2(fmaf(fE, sA, c_E2));
                    const float qpref = R2 * fmaf(e2p * E2, kp * p, qpmax_);
                    sA += clip1e5(qpref);
                    ob0[i] = sA;
                }
                {
                    const float p = P1[i];
                    const float e2  = ex2(-L2E10 * sB);
                    const float e2p = ex2c(fmaf(-L2E10, sB, c_2p));
                    const float R2  = rcpf((1.0f + e2) * (1.0f + e2p));
                    const float E2  = ex2(fmaf(fE, sB, c_E2));
                    const float qpref = R2 * fmaf(e2p * E2, kp * p, qpmax_);
                    sB += clip1e5(qpref);
                    ob1[i] = sB;
                }
            }
            if (use_ws) { plane_store(w2a, ob0, c); plane_store(w2b, ob1, c); }
            else {
                #pragma unroll
                for (int i = 0; i < CHUNK; ++i) {
                    op0[(c * CHUNK + i) * 5 + 2] = ob0[i];
                    op1[(c * CHUNK + i) * 5 + 2] = ob1[i];
                }
            }
        };
        pf(a0, a1, 0);
        for (int c = 0; c < NCHUNK; c += 2) {
            pf(q0, q1, c + 1);
            cw(a0, a1, c);
            if (c + 2 < NCHUNK) pf(a0, a1, c + 2);
            cw(q0, q1, c + 1);
        }
    } else {
        // ---- s4: 4 trans/step/chain ----
        float sA = 0.f, sB = 0.f;
        float a0[CHUNK], a1[CHUNK], q0[CHUNK], q1[CHUNK];
        float* w4a = wbase + 4 * BT + (size_t)b0 * NT;
        float* w4b = wbase + 4 * BT + (size_t)b1 * NT;
        auto pf = [&](float* P0, float* P1, int c) {
            #pragma unroll
            for (int i = 0; i < CHUNK; ++i) {
                P0[i] = ip0[(c * CHUNK + i) * 3 + 0];
                P1[i] = ip1[(c * CHUNK + i) * 3 + 0];
            }
        };
        auto cw = [&](const float* P0, const float* P1, int c) {
            float ob0[CHUNK], ob1[CHUNK];
            #pragma unroll
            for (int i = 0; i < CHUNK; ++i) {
                {
                    const float p = P0[i];
                    const float e4  = ex2(-L2E10 * sA);
                    const float e4s = ex2c(fmaf(-L2E10, sA, c_4s));
                    const float R4  = rcpf((1.0f + e4) * (1.0f + e4s));
                    const float E4  = ex2(fmaf(fE, sA, c_E4));
                    const float pl  = p * fmaf(p, Kn_, Kl_);
                    const float qslow = R4 * fmaf(e4s * E4, pl, qgmax_);
                    sA += clip1e5(qslow);
                    ob0[i] = sA;
                }
                {
                    const float p = P1[i];
                    const float e4  = ex2(-L2E10 * sB);
                    const float e4s = ex2c(fmaf(-L2E10, sB, c_4s));
                    const float R4  = rcpf((1.0f + e4) * (1.0f + e4s));
                    const float E4  = ex2(fmaf(fE, sB, c_E4));
                    const float pl  = p * fmaf(p, Kn_, Kl_);
                    const float qslow = R4 * fmaf(e4s * E4, pl, qgmax_);
                    sB += clip1e5(qslow);
                    ob1[i] = sB;
                }
            }
            if (use_ws) { plane_store(w4a, ob0, c); plane_store(w4b, ob1, c); }
            else {
                #pragma unroll
                for (int i = 0; i < CHUNK; ++i) {
                    op0[(c * CHUNK + i) * 5 + 4] = ob0[i];
                    op1[(c * CHUNK + i) * 5 + 4] = ob1[i];
                }
            }
        };
        pf(a0, a1, 0);
        for (int c = 0; c < NCHUNK; c += 2) {
            pf(q0, q1, c + 1);
            cw(a0, a1, c);
            if (c + 2 < NCHUNK) pf(a0, a1, c + 2);
            cw(q0, q1, c + 1);
        }
    }
}

// ---- SoA planes -> AoS out. One thread per 4 timesteps of one chain. ----
__global__ __launch_bounds__(256)
void tx_kernel(const float* __restrict__ wsp, float* __restrict__ out) {
    const size_t idx = (size_t)blockIdx.x * 256 + threadIdx.x;  // BT/4 threads
    const size_t b  = idx / (NT / 4);
    const size_t t0 = (idx % (NT / 4)) * 4;
    const float* base = wsp + b * NT + t0;
    const float4 v0 = *(const float4*)(base + 0 * BT);
    const float4 v1 = *(const float4*)(base + 1 * BT);
    const float4 v2 = *(const float4*)(base + 2 * BT);
    const float4 v3 = *(const float4*)(base + 3 * BT);
    const float4 v4 = *(const float4*)(base + 4 * BT);
    float4* o = (float4*)(out + (b * NT + t0) * 5);
    o[0] = make_float4(v0.x, v1.x, v2.x, v3.x);
    o[1] = make_float4(v4.x, v0.y, v1.y, v2.y);
    o[2] = make_float4(v3.y, v4.y, v0.z, v1.z);
    o[3] = make_float4(v2.z, v3.z, v4.z, v0.w);
    o[4] = make_float4(v1.w, v2.w, v3.w, v4.w);
}

extern "C" void kernel_launch(void* const* d_in, const int* in_sizes, int n_in,
                              void* d_out, int out_size, void* d_ws, size_t ws_size,
                              hipStream_t stream) {
    const float* inp   = (const float*)d_in[0];
    const float* theta = (const float*)d_in[1];
    float* out = (float*)d_out;
    float* wsp = (float*)d_ws;
    const int use_ws = (wsp != nullptr && ws_size >= 5 * sizeof(float) * BT) ? 1 : 0;
    // 4 roles x 32 chain-groups (128 chains each: 64 lanes x 2 chains/lane)
    prnn_roles<<<4 * (NB / 128), 64, 0, stream>>>(inp, theta, out, wsp, use_ws);
    if (use_ws)
        tx_kernel<<<(int)(BT / 4 / 256), 256, 0, stream>>>(wsp, out);
}

// Round 8
// 617.856 us; speedup vs baseline: 1.3877x; 1.3877x over previous
//
#include <hip/hip_runtime.h>

// PRNNLayer: B=4096 chains x T=2048 steps, 5 states.
// R10: R8 (one role per block, 256 blocks x 64 thr, SoA planes in ws + tx,
// no barriers) + INPUT-ONLY PRECOMPUTE staged through `out` as scratch.
// Evidence: R9 (2 chains/thread) ran at identical per-chain-step cost ->
// per-wave wall is instruction/trans-pipe OCCUPANCY, not latency. So the 5
// input-only trans ops (pe 2, psnow 2, dm 1) + ~15-VALU PET chain in role 1
// are real cost (~176 cyc/step of trans occupancy for 11 trans). Hoist them:
//   pre:   fully parallel, writes planes {pe,psnow,prain,dm,mdd} into OUT
//          (dead until tx overwrites it; kernel boundaries order everything)
//   roles: role1 reads 5 coalesced streams, 6 trans/step, ~38 insts/step
//   tx:    wsp planes -> AoS out (unchanged)
// Roles 0/2/3 verbatim R8. No barriers anywhere. Fallback (no ws): R8 path.

#define NB 4096
#define NT 2048
#define CHUNK 16
#define NCHUNK (NT / CHUNK)   // 128 (roles 0,2,3)
#define K1 8
#define NCH1 (NT / K1)        // 256 (role 1)
#define BT ((size_t)NB * (size_t)NT)

#define L2E10 14.4269504089f  // 10*log2(e)  (hv(x) = sigmoid(10x))
#define L2E    1.44269504089f

__device__ __forceinline__ float rcpf(float x) { return __builtin_amdgcn_rcpf(x); }
__device__ __forceinline__ float ex2(float a)  { return __builtin_amdgcn_exp2f(a); }
__device__ __forceinline__ float ex2c(float a) { return __builtin_amdgcn_exp2f(fminf(a, 80.0f)); }
__device__ __forceinline__ float clip1e5(float x) {
    return __builtin_amdgcn_fmed3f(x, -100000.0f, 100000.0f);
}

// ---------------- Pass 0: input-only terms -> OUT-as-scratch planes --------
// plane0=pe plane1=psnow plane2=prain plane3=dm plane4=mdd (=ddf*(tm-tmax))
__global__ __launch_bounds__(256)
void pre_kernel(const float* __restrict__ inp, const float* __restrict__ theta,
                float* __restrict__ scr) {
    const float ddf_  = theta[3] * 5.0f;
    const float tmin_ = theta[4] * -3.0f;
    const float tmax_ = theta[5] * 3.0f;
    const float c_sn  = -L2E10 * tmin_;
    const float c_m   =  L2E10 * tmax_;
    const float c_dd  = -ddf_ * tmax_;

    const size_t k = (size_t)blockIdx.x * 256 + threadIdx.x;
    const float p  = inp[k * 3 + 0];
    const float tm = inp[k * 3 + 1];
    const float dl = inp[k * 3 + 2];

    const float A1 = tm + 237.3f;
    const float A2 = tm + 273.2f;
    const float q  = rcpf(A1 * A2);
    const float pe = 436.98672f * dl * ex2(24.958624f * tm * (q * A2)) * (q * A1);
    const float psnow = rcpf(1.0f + ex2(fmaf(L2E10, tm, c_sn))) * p;
    const float prain = p - psnow;
    const float dm  = 1.0f + ex2(fmaf(-L2E10, tm, c_m));
    const float mdd = fmaf(ddf_, tm, c_dd);

    scr[0 * BT + k] = pe;
    scr[1 * BT + k] = psnow;
    scr[2 * BT + k] = prain;
    scr[3 * BT + k] = dm;
    scr[4 * BT + k] = mdd;
}

// ---------------- Pass 1: role-decomposed serial scans ----------------------
__global__ __launch_bounds__(64, 1)
void prnn_roles(const float* __restrict__ inp, const float* __restrict__ theta,
                float* __restrict__ out, float* __restrict__ wsp, int use_ws) {
    const int lane = threadIdx.x;
    const int role = blockIdx.x & 3;
    const int b = (blockIdx.x >> 2) * 64 + lane;

    const float f_     = theta[0] * 0.1f;
    const float smax_  = theta[1] * 1950.0f;
    const float qmax_  = theta[2] * 50.0f;
    const float ddf_   = theta[3] * 5.0f;
    const float tmin_  = theta[4] * -3.0f;
    const float tmax_  = theta[5] * 3.0f;
    const float Kc_    = theta[6] * 0.5f;
    const float SCmax_ = theta[7] * 1.5f;
    const float spmax_ = theta[8] * 1950.0f;
    const float qpmax_ = theta[9] * 40.0f;
    const float kp     = theta[10];
    const float sgmax_ = theta[11] * 1950.0f;
    const float qgmax_ = theta[12] * 40.0f;
    const float Kl_    = theta[13] * 0.5f;
    const float Kn_    = theta[14] * 0.5f;

    const float inv_smax = rcpf(smax_);
    const float KcDc  = Kc_ * 0.849932f;          // Kc_ * 0.986*0.862
    const float c_sn  = -L2E10 * tmin_;
    const float c_m   =  L2E10 * tmax_;
    const float c_dd  = -ddf_ * tmax_;
    const float c_sc1 =  L2E10 * SCmax_ * 1.4f;
    const float c_sc0 =  L2E10 * SCmax_ * 0.6f;
    const float c_2p  =  L2E10 * spmax_;
    const float c_3s  =  L2E10 * smax_;
    const float c_4s  =  L2E10 * sgmax_;
    const float fE    = f_ * L2E;
    const float c_E2  = -fE * spmax_;
    const float c_E3  = -fE * smax_;
    const float c_E4  = -fE * sgmax_;

    const float* ip = inp + (size_t)b * (NT * 3);
    float*       op = out + (size_t)b * (NT * 5);
    float* wbase = use_ws ? wsp : out;

    auto plane_store16 = [&](float* plane, const float* ob, int off) {
        float4* d = (float4*)(plane + (size_t)off);
        const float4* s = (const float4*)ob;
        #pragma unroll
        for (int i = 0; i < 4; ++i) d[i] = s[i];
    };

    if (role == 0) {
        // ---- s0 (verbatim R8) ----
        float s0 = 0.f;
        float bA[CHUNK * 3], bB[CHUNK * 3];
        float* w0 = wbase + 0 * BT + (size_t)b * NT;
        auto pf = [&](float* d, int c) {
            const float4* s = (const float4*)(ip + (size_t)c * (CHUNK * 3));
            #pragma unroll
            for (int i = 0; i < (CHUNK * 3) / 4; ++i) ((float4*)d)[i] = s[i];
        };
        auto cw = [&](const float* d, int c) {
            float ob[CHUNK];
            #pragma unroll
            for (int i = 0; i < CHUNK; ++i) {
                const float p  = d[i * 3 + 0];
                const float dl = d[i * 3 + 2];
                const float day = rcpf(1.0f + ex2(fmaf(-L2E10, dl, 7.21347520f)));
                const float da  = 1.0f + ex2(fmaf(-L2E10, p, L2E));
                const float lai   = fmaf(0.328f, day, 0.15f);
                const float kcf   = fmaf(0.6f, day, 0.4f);
                const float kterm = KcDc * kcf * lai;
                const float zday  = fmaf(c_sc1, day, c_sc0);
                const float e0  = ex2(-L2E10 * s0);
                const float esc = ex2(fmaf(-L2E10, s0, zday));
                const float d0  = 1.0f + e0;
                const float dsc = 1.0f + esc;
                const float Rp  = rcpf(da * d0 * dsc);
                const float pintc = Rp * fmaf(d0 * esc, kterm, p);
                s0 += clip1e5(pintc);
                ob[i] = s0;
            }
            if (use_ws) plane_store16(w0, ob, c * CHUNK);
            else {
                #pragma unroll
                for (int i = 0; i < CHUNK; ++i) op[(c * CHUNK + i) * 5 + 0] = ob[i];
            }
        };
        pf(bA, 0);
        for (int c = 0; c < NCHUNK; c += 2) {
            pf(bB, c + 1);
            cw(bA, c);
            if (c + 2 < NCHUNK) pf(bA, c + 2);
            cw(bB, c + 1);
        }
    } else if (role == 1) {
        // ---- s1 + s3 (critical role) ----
        float s1 = 0.f, s3 = 0.f;
        float* w1 = wbase + 1 * BT + (size_t)b * NT;
        float* w3 = wbase + 3 * BT + (size_t)b * NT;
        if (use_ws) {
            // scratch planes (written by pre into OUT)
            const float* PE = out + 0 * BT + (size_t)b * NT;
            const float* PS = out + 1 * BT + (size_t)b * NT;
            const float* PR = out + 2 * BT + (size_t)b * NT;
            const float* DM = out + 3 * BT + (size_t)b * NT;
            const float* MD = out + 4 * BT + (size_t)b * NT;
            float peA[K1], psA[K1], prA[K1], dmA[K1], mdA[K1];
            float peB[K1], psB[K1], prB[K1], dmB[K1], mdB[K1];
            float ob1[2 * K1], ob3[2 * K1];
            auto pf = [&](float* pe_, float* ps_, float* pr_, float* dm_,
                          float* md_, int c) {
                const int o = c * K1;
                #pragma unroll
                for (int i = 0; i < K1 / 4; ++i) {
                    ((float4*)pe_)[i] = *(const float4*)(PE + o + i * 4);
                    ((float4*)ps_)[i] = *(const float4*)(PS + o + i * 4);
                    ((float4*)pr_)[i] = *(const float4*)(PR + o + i * 4);
                    ((float4*)dm_)[i] = *(const float4*)(DM + o + i * 4);
                    ((float4*)md_)[i] = *(const float4*)(MD + o + i * 4);
                }
            };
            auto cw = [&](const float* pe_, const float* ps_, const float* pr_,
                          const float* dm_, const float* md_, int half) {
                #pragma unroll
                for (int i = 0; i < K1; ++i) {
                    const float pe = pe_[i], psnow = ps_[i], prain = pr_[i];
                    const float dm = dm_[i], mdd = md_[i];
                    const float e1 = ex2(-L2E10 * s1);
                    const float melt = rcpf(dm * (1.0f + e1)) * fminf(s1, mdd);
                    const float e3  = ex2(-L2E10 * s3);
                    const float e3s = ex2c(fmaf(-L2E10, s3, c_3s));
                    const float R3  = rcpf((1.0f + e3) * (1.0f + e3s));
                    const float E3  = ex2(fmaf(fE, s3, c_E3));
                    const float t_et = pe * fmaf(e3s * s3, inv_smax, 1.0f);
                    const float t_qs = qmax_ * fmaf(e3s, E3, 1.0f);
                    const float outflux = R3 * (t_et + t_qs + (s3 - smax_));
                    const float ds3 = prain + melt - outflux;
                    s1 += clip1e5(psnow - melt);
                    s3 += clip1e5(ds3);
                    ob1[half * K1 + i] = s1;
                    ob3[half * K1 + i] = s3;
                }
            };
            pf(peA, psA, prA, dmA, mdA, 0);
            for (int c = 0; c < NCH1; c += 2) {
                pf(peB, psB, prB, dmB, mdB, c + 1);
                cw(peA, psA, prA, dmA, mdA, 0);
                if (c + 2 < NCH1) pf(peA, psA, prA, dmA, mdA, c + 2);
                cw(peB, psB, prB, dmB, mdB, 1);
                plane_store16(w1, ob1, c * K1);   // 64B line per 2 chunks
                plane_store16(w3, ob3, c * K1);
            }
        } else {
            // fallback: verbatim R8 (inline input-only terms, AoS stores)
            float bA[CHUNK * 3], bB[CHUNK * 3];
            auto pf = [&](float* d, int c) {
                const float4* s = (const float4*)(ip + (size_t)c * (CHUNK * 3));
                #pragma unroll
                for (int i = 0; i < (CHUNK * 3) / 4; ++i) ((float4*)d)[i] = s[i];
            };
            auto cw = [&](const float* d, int c) {
                #pragma unroll
                for (int i = 0; i < CHUNK; ++i) {
                    const float p  = d[i * 3 + 0];
                    const float tm = d[i * 3 + 1];
                    const float dl = d[i * 3 + 2];
                    const float A1 = tm + 237.3f;
                    const float A2 = tm + 273.2f;
                    const float qq = rcpf(A1 * A2);
                    const float pe = 436.98672f * dl * ex2(24.958624f * tm * (qq * A2)) * (qq * A1);
                    const float psnow = rcpf(1.0f + ex2(fmaf(L2E10, tm, c_sn))) * p;
                    const float dm = 1.0f + ex2(fmaf(-L2E10, tm, c_m));
                    const float prain = p - psnow;
                    const float e1 = ex2(-L2E10 * s1);
                    const float melt = rcpf(dm * (1.0f + e1))
                                       * fminf(s1, fmaf(ddf_, tm, c_dd));
                    const float e3  = ex2(-L2E10 * s3);
                    const float e3s = ex2c(fmaf(-L2E10, s3, c_3s));
                    const float R3  = rcpf((1.0f + e3) * (1.0f + e3s));
                    const float E3  = ex2(fmaf(fE, s3, c_E3));
                    const float t_et = pe * fmaf(e3s * s3, inv_smax, 1.0f);
                    const float t_qs = qmax_ * fmaf(e3s, E3, 1.0f);
                    const float outflux = R3 * (t_et + t_qs + (s3 - smax_));
                    const float ds3 = prain + melt - outflux;
                    s1 += clip1e5(psnow - melt);
                    s3 += clip1e5(ds3);
                    const int t = c * CHUNK + i;
                    op[t * 5 + 1] = s1;
                    op[t * 5 + 3] = s3;
                }
            };
            pf(bA, 0);
            for (int c = 0; c < NCHUNK; c += 2) {
                pf(bB, c + 1);
                cw(bA, c);
                if (c + 2 < NCHUNK) pf(bA, c + 2);
                cw(bB, c + 1);
            }
        }
    } else if (role == 2) {
        // ---- s2 (verbatim R8) ----
        float s2 = 0.f;
        float pA[CHUNK], pB[CHUNK];
        float* w2 = wbase + 2 * BT + (size_t)b * NT;
        auto pf = [&](float* P, int c) {
            #pragma unroll
            for (int i = 0; i < CHUNK; ++i) P[i] = ip[(c * CHUNK + i) * 3 + 0];
        };
        auto cw = [&](const float* P, int c) {
            float ob[CHUNK];
            #pragma unroll
            for (int i = 0; i < CHUNK; ++i) {
                const float p = P[i];
                const float e2  = ex2(-L2E10 * s2);
                const float e2p = ex2c(fmaf(-L2E10, s2, c_2p));
                const float R2  = rcpf((1.0f + e2) * (1.0f + e2p));
                const float E2  = ex2(fmaf(fE, s2, c_E2));
                const float qpref = R2 * fmaf(e2p * E2, kp * p, qpmax_);
                s2 += clip1e5(qpref);
                ob[i] = s2;
            }
            if (use_ws) plane_store16(w2, ob, c * CHUNK);
            else {
                #pragma unroll
                for (int i = 0; i < CHUNK; ++i) op[(c * CHUNK + i) * 5 + 2] = ob[i];
            }
        };
        pf(pA, 0);
        for (int c = 0; c < NCHUNK; c += 2) {
            pf(pB, c + 1);
            cw(pA, c);
            if (c + 2 < NCHUNK) pf(pA, c + 2);
            cw(pB, c + 1);
        }
    } else {
        // ---- s4 (verbatim R8) ----
        float s4 = 0.f;
        float pA[CHUNK], pB[CHUNK];
        float* w4 = wbase + 4 * BT + (size_t)b * NT;
        auto pf = [&](float* P, int c) {
            #pragma unroll
            for (int i = 0; i < CHUNK; ++i) P[i] = ip[(c * CHUNK + i) * 3 + 0];
        };
        auto cw = [&](const float* P, int c) {
            float ob[CHUNK];
            #pragma unroll
            for (int i = 0; i < CHUNK; ++i) {
                const float p = P[i];
                const float e4  = ex2(-L2E10 * s4);
                const float e4s = ex2c(fmaf(-L2E10, s4, c_4s));
                const float R4  = rcpf((1.0f + e4) * (1.0f + e4s));
                const float E4  = ex2(fmaf(fE, s4, c_E4));
                const float pl  = p * fmaf(p, Kn_, Kl_);
                const float qslow = R4 * fmaf(e4s * E4, pl, qgmax_);
                s4 += clip1e5(qslow);
                ob[i] = s4;
            }
            if (use_ws) plane_store16(w4, ob, c * CHUNK);
            else {
                #pragma unroll
                for (int i = 0; i < CHUNK; ++i) op[(c * CHUNK + i) * 5 + 4] = ob[i];
            }
        };
        pf(pA, 0);
        for (int c = 0; c < NCHUNK; c += 2) {
            pf(pB, c + 1);
            cw(pA, c);
            if (c + 2 < NCHUNK) pf(pA, c + 2);
            cw(pB, c + 1);
        }
    }
}

// ---- Pass 2: SoA planes -> AoS out (verbatim R8) ----
__global__ __launch_bounds__(256)
void tx_kernel(const float* __restrict__ wsp, float* __restrict__ out) {
    const size_t idx = (size_t)blockIdx.x * 256 + threadIdx.x;  // BT/4 threads
    const size_t b  = idx / (NT / 4);
    const size_t t0 = (idx % (NT / 4)) * 4;
    const float* base = wsp + b * NT + t0;
    const float4 v0 = *(const float4*)(base + 0 * BT);
    const float4 v1 = *(const float4*)(base + 1 * BT);
    const float4 v2 = *(const float4*)(base + 2 * BT);
    const float4 v3 = *(const float4*)(base + 3 * BT);
    const float4 v4 = *(const float4*)(base + 4 * BT);
    float4* o = (float4*)(out + (b * NT + t0) * 5);
    o[0] = make_float4(v0.x, v1.x, v2.x, v3.x);
    o[1] = make_float4(v4.x, v0.y, v1.y, v2.y);
    o[2] = make_float4(v3.y, v4.y, v0.z, v1.z);
    o[3] = make_float4(v2.z, v3.z, v4.z, v0.w);
    o[4] = make_float4(v1.w, v2.w, v3.w, v4.w);
}

extern "C" void kernel_launch(void* const* d_in, const int* in_sizes, int n_in,
                              void* d_out, int out_size, void* d_ws, size_t ws_size,
                              hipStream_t stream) {
    const float* inp   = (const float*)d_in[0];
    const float* theta = (const float*)d_in[1];
    float* out = (float*)d_out;
    float* wsp = (float*)d_ws;
    const int use_ws = (wsp != nullptr && ws_size >= 5 * sizeof(float) * BT) ? 1 : 0;
    if (use_ws)
        pre_kernel<<<(int)(BT / 256), 256, 0, stream>>>(inp, theta, out);
    prnn_roles<<<4 * (NB / 64), 64, 0, stream>>>(inp, theta, out, wsp, use_ws);
    if (use_ws)
        tx_kernel<<<(int)(BT / 4 / 256), 256, 0, stream>>>(wsp, out);
}

// Round 9
// 567.495 us; speedup vs baseline: 1.5109x; 1.0887x over previous
//
#include <hip/hip_runtime.h>

// PRNNLayer: B=4096 chains x T=2048 steps, 5 states.
// R11: R10 structure (pre -> planes in OUT scratch; roles one-per-block;
// SoA planes in ws + tx; no barriers) with SCHEDULING-ONLY fixes:
//  1) asm-volatile PINS on every staged buffer, placed right before its
//     consuming cw: forces buffer values to be register-resident there, so
//     the compiler cannot sink the loads into the compute (the R8/R10
//     VGPR=68 < buffer size proved the double-buffer was being destroyed;
//     cost was ~6k cyc per chunk-iter independent of work = exposed memory
//     latency every few steps).
//  2) CHUNK 16->32 (roles 0/2/3), K1 8->16 (role 1): VGPRs are free at
//     1 wave/SIMD (256 waves total on 1024 SIMDs; HW allows up to 512).
// All arithmetic verbatim from the verified R10 kernel.

#define NB 4096
#define NT 2048
#define CHUNK 32
#define NCHUNK (NT / CHUNK)   // 64 (roles 0,2,3)
#define K1 16
#define NCH1 (NT / K1)        // 128 (role 1)
#define BT ((size_t)NB * (size_t)NT)

#define L2E10 14.4269504089f  // 10*log2(e)  (hv(x) = sigmoid(10x))
#define L2E    1.44269504089f

__device__ __forceinline__ float rcpf(float x) { return __builtin_amdgcn_rcpf(x); }
__device__ __forceinline__ float ex2(float a)  { return __builtin_amdgcn_exp2f(a); }
__device__ __forceinline__ float ex2c(float a) { return __builtin_amdgcn_exp2f(fminf(a, 80.0f)); }
__device__ __forceinline__ float clip1e5(float x) {
    return __builtin_amdgcn_fmed3f(x, -100000.0f, 100000.0f);
}
// Pin n4 float4s of a staged buffer into live VGPRs at this program point.
// Empty asm: zero instructions, but inputs must be materialized here, so the
// feeding loads complete before this point and cannot be sunk below it.
__device__ __forceinline__ void pinbuf(const float* d, int n4) {
    const float4* v = (const float4*)d;
    #pragma unroll
    for (int i = 0; i < n4; ++i)
        asm volatile("" :: "v"(v[i].x), "v"(v[i].y), "v"(v[i].z), "v"(v[i].w));
}

// ---------------- Pass 0: input-only terms -> OUT-as-scratch planes --------
// plane0=pe plane1=psnow plane2=prain plane3=dm plane4=mdd (=ddf*(tm-tmax))
__global__ __launch_bounds__(256)
void pre_kernel(const float* __restrict__ inp, const float* __restrict__ theta,
                float* __restrict__ scr) {
    const float ddf_  = theta[3] * 5.0f;
    const float tmin_ = theta[4] * -3.0f;
    const float tmax_ = theta[5] * 3.0f;
    const float c_sn  = -L2E10 * tmin_;
    const float c_m   =  L2E10 * tmax_;
    const float c_dd  = -ddf_ * tmax_;

    const size_t k = (size_t)blockIdx.x * 256 + threadIdx.x;
    const float p  = inp[k * 3 + 0];
    const float tm = inp[k * 3 + 1];
    const float dl = inp[k * 3 + 2];

    const float A1 = tm + 237.3f;
    const float A2 = tm + 273.2f;
    const float q  = rcpf(A1 * A2);
    const float pe = 436.98672f * dl * ex2(24.958624f * tm * (q * A2)) * (q * A1);
    const float psnow = rcpf(1.0f + ex2(fmaf(L2E10, tm, c_sn))) * p;
    const float prain = p - psnow;
    const float dm  = 1.0f + ex2(fmaf(-L2E10, tm, c_m));
    const float mdd = fmaf(ddf_, tm, c_dd);

    scr[0 * BT + k] = pe;
    scr[1 * BT + k] = psnow;
    scr[2 * BT + k] = prain;
    scr[3 * BT + k] = dm;
    scr[4 * BT + k] = mdd;
}

// ---------------- Pass 1: role-decomposed serial scans ----------------------
__global__ __launch_bounds__(64, 1)
void prnn_roles(const float* __restrict__ inp, const float* __restrict__ theta,
                float* __restrict__ out, float* __restrict__ wsp, int use_ws) {
    const int lane = threadIdx.x;
    const int role = blockIdx.x & 3;
    const int b = (blockIdx.x >> 2) * 64 + lane;

    const float f_     = theta[0] * 0.1f;
    const float smax_  = theta[1] * 1950.0f;
    const float qmax_  = theta[2] * 50.0f;
    const float ddf_   = theta[3] * 5.0f;
    const float tmin_  = theta[4] * -3.0f;
    const float tmax_  = theta[5] * 3.0f;
    const float Kc_    = theta[6] * 0.5f;
    const float SCmax_ = theta[7] * 1.5f;
    const float spmax_ = theta[8] * 1950.0f;
    const float qpmax_ = theta[9] * 40.0f;
    const float kp     = theta[10];
    const float sgmax_ = theta[11] * 1950.0f;
    const float qgmax_ = theta[12] * 40.0f;
    const float Kl_    = theta[13] * 0.5f;
    const float Kn_    = theta[14] * 0.5f;

    const float inv_smax = rcpf(smax_);
    const float KcDc  = Kc_ * 0.849932f;          // Kc_ * 0.986*0.862
    const float c_sn  = -L2E10 * tmin_;
    const float c_m   =  L2E10 * tmax_;
    const float c_dd  = -ddf_ * tmax_;
    const float c_sc1 =  L2E10 * SCmax_ * 1.4f;
    const float c_sc0 =  L2E10 * SCmax_ * 0.6f;
    const float c_2p  =  L2E10 * spmax_;
    const float c_3s  =  L2E10 * smax_;
    const float c_4s  =  L2E10 * sgmax_;
    const float fE    = f_ * L2E;
    const float c_E2  = -fE * spmax_;
    const float c_E3  = -fE * smax_;
    const float c_E4  = -fE * sgmax_;

    const float* ip = inp + (size_t)b * (NT * 3);
    float*       op = out + (size_t)b * (NT * 5);
    float* wbase = use_ws ? wsp : out;

    auto plane_storeN = [&](float* plane, const float* ob, int off, int n4) {
        float4* d = (float4*)(plane + (size_t)off);
        const float4* s = (const float4*)ob;
        #pragma unroll
        for (int i = 0; i < 8; ++i) { if (i < n4) d[i] = s[i]; }
    };

    if (role == 0) {
        // ---- s0 (arithmetic verbatim) ----
        float s0 = 0.f;
        float bA[CHUNK * 3], bB[CHUNK * 3];
        float* w0 = wbase + 0 * BT + (size_t)b * NT;
        auto pf = [&](float* d, int c) {
            const float4* s = (const float4*)(ip + (size_t)c * (CHUNK * 3));
            #pragma unroll
            for (int i = 0; i < (CHUNK * 3) / 4; ++i) ((float4*)d)[i] = s[i];
        };
        auto cw = [&](const float* d, int c) {
            float ob[CHUNK];
            #pragma unroll
            for (int i = 0; i < CHUNK; ++i) {
                const float p  = d[i * 3 + 0];
                const float dl = d[i * 3 + 2];
                const float day = rcpf(1.0f + ex2(fmaf(-L2E10, dl, 7.21347520f)));
                const float da  = 1.0f + ex2(fmaf(-L2E10, p, L2E));
                const float lai   = fmaf(0.328f, day, 0.15f);
                const float kcf   = fmaf(0.6f, day, 0.4f);
                const float kterm = KcDc * kcf * lai;
                const float zday  = fmaf(c_sc1, day, c_sc0);
                const float e0  = ex2(-L2E10 * s0);
                const float esc = ex2(fmaf(-L2E10, s0, zday));
                const float d0  = 1.0f + e0;
                const float dsc = 1.0f + esc;
                const float Rp  = rcpf(da * d0 * dsc);
                const float pintc = Rp * fmaf(d0 * esc, kterm, p);
                s0 += clip1e5(pintc);
                ob[i] = s0;
            }
            if (use_ws) plane_storeN(w0, ob, c * CHUNK, CHUNK / 4);
            else {
                #pragma unroll
                for (int i = 0; i < CHUNK; ++i) op[(c * CHUNK + i) * 5 + 0] = ob[i];
            }
        };
        pf(bA, 0);
        for (int c = 0; c < NCHUNK; c += 2) {
            pf(bB, c + 1);
            pinbuf(bA, (CHUNK * 3) / 4);
            cw(bA, c);
            if (c + 2 < NCHUNK) pf(bA, c + 2);
            pinbuf(bB, (CHUNK * 3) / 4);
            cw(bB, c + 1);
        }
    } else if (role == 1) {
        // ---- s1 + s3 (critical role) ----
        float s1 = 0.f, s3 = 0.f;
        float* w1 = wbase + 1 * BT + (size_t)b * NT;
        float* w3 = wbase + 3 * BT + (size_t)b * NT;
        if (use_ws) {
            const float* PE = out + 0 * BT + (size_t)b * NT;
            const float* PS = out + 1 * BT + (size_t)b * NT;
            const float* PR = out + 2 * BT + (size_t)b * NT;
            const float* DM = out + 3 * BT + (size_t)b * NT;
            const float* MD = out + 4 * BT + (size_t)b * NT;
            float peA[K1], psA[K1], prA[K1], dmA[K1], mdA[K1];
            float peB[K1], psB[K1], prB[K1], dmB[K1], mdB[K1];
            float ob1[2 * K1], ob3[2 * K1];
            auto pf = [&](float* pe_, float* ps_, float* pr_, float* dm_,
                          float* md_, int c) {
                const int o = c * K1;
                #pragma unroll
                for (int i = 0; i < K1 / 4; ++i) {
                    ((float4*)pe_)[i] = *(const float4*)(PE + o + i * 4);
                    ((float4*)ps_)[i] = *(const float4*)(PS + o + i * 4);
                    ((float4*)pr_)[i] = *(const float4*)(PR + o + i * 4);
                    ((float4*)dm_)[i] = *(const float4*)(DM + o + i * 4);
                    ((float4*)md_)[i] = *(const float4*)(MD + o + i * 4);
                }
            };
            auto pin5 = [&](const float* pe_, const float* ps_, const float* pr_,
                            const float* dm_, const float* md_) {
                pinbuf(pe_, K1 / 4); pinbuf(ps_, K1 / 4); pinbuf(pr_, K1 / 4);
                pinbuf(dm_, K1 / 4); pinbuf(md_, K1 / 4);
            };
            auto cw = [&](const float* pe_, const float* ps_, const float* pr_,
                          const float* dm_, const float* md_, int half) {
                #pragma unroll
                for (int i = 0; i < K1; ++i) {
                    const float pe = pe_[i], psnow = ps_[i], prain = pr_[i];
                    const float dm = dm_[i], mdd = md_[i];
                    const float e1 = ex2(-L2E10 * s1);
                    const float melt = rcpf(dm * (1.0f + e1)) * fminf(s1, mdd);
                    const float e3  = ex2(-L2E10 * s3);
                    const float e3s = ex2c(fmaf(-L2E10, s3, c_3s));
                    const float R3  = rcpf((1.0f + e3) * (1.0f + e3s));
                    const float E3  = ex2(fmaf(fE, s3, c_E3));
                    const float t_et = pe * fmaf(e3s * s3, inv_smax, 1.0f);
                    const float t_qs = qmax_ * fmaf(e3s, E3, 1.0f);
                    const float outflux = R3 * (t_et + t_qs + (s3 - smax_));
                    const float ds3 = prain + melt - outflux;
                    s1 += clip1e5(psnow - melt);
                    s3 += clip1e5(ds3);
                    ob1[half * K1 + i] = s1;
                    ob3[half * K1 + i] = s3;
                }
            };
            pf(peA, psA, prA, dmA, mdA, 0);
            for (int c = 0; c < NCH1; c += 2) {
                pf(peB, psB, prB, dmB, mdB, c + 1);
                pin5(peA, psA, prA, dmA, mdA);
                cw(peA, psA, prA, dmA, mdA, 0);
                if (c + 2 < NCH1) pf(peA, psA, prA, dmA, mdA, c + 2);
                pin5(peB, psB, prB, dmB, mdB);
                cw(peB, psB, prB, dmB, mdB, 1);
                plane_storeN(w1, ob1, c * K1, (2 * K1) / 4);
                plane_storeN(w3, ob3, c * K1, (2 * K1) / 4);
            }
        } else {
            // fallback: inline input-only terms, AoS stores (verbatim)
            float bA[CHUNK * 3], bB[CHUNK * 3];
            auto pf = [&](float* d, int c) {
                const float4* s = (const float4*)(ip + (size_t)c * (CHUNK * 3));
                #pragma unroll
                for (int i = 0; i < (CHUNK * 3) / 4; ++i) ((float4*)d)[i] = s[i];
            };
            auto cw = [&](const float* d, int c) {
                #pragma unroll
                for (int i = 0; i < CHUNK; ++i) {
                    const float p  = d[i * 3 + 0];
                    const float tm = d[i * 3 + 1];
                    const float dl = d[i * 3 + 2];
                    const float A1 = tm + 237.3f;
                    const float A2 = tm + 273.2f;
                    const float qq = rcpf(A1 * A2);
                    const float pe = 436.98672f * dl * ex2(24.958624f * tm * (qq * A2)) * (qq * A1);
                    const float psnow = rcpf(1.0f + ex2(fmaf(L2E10, tm, c_sn))) * p;
                    const float dm = 1.0f + ex2(fmaf(-L2E10, tm, c_m));
                    const float prain = p - psnow;
                    const float e1 = ex2(-L2E10 * s1);
                    const float melt = rcpf(dm * (1.0f + e1))
                                       * fminf(s1, fmaf(ddf_, tm, c_dd));
                    const float e3  = ex2(-L2E10 * s3);
                    const float e3s = ex2c(fmaf(-L2E10, s3, c_3s));
                    const float R3  = rcpf((1.0f + e3) * (1.0f + e3s));
                    const float E3  = ex2(fmaf(fE, s3, c_E3));
                    const float t_et = pe * fmaf(e3s * s3, inv_smax, 1.0f);
                    const float t_qs = qmax_ * fmaf(e3s, E3, 1.0f);
                    const float outflux = R3 * (t_et + t_qs + (s3 - smax_));
                    const float ds3 = prain + melt - outflux;
                    s1 += clip1e5(psnow - melt);
                    s3 += clip1e5(ds3);
                    const int t = c * CHUNK + i;
                    op[t * 5 + 1] = s1;
                    op[t * 5 + 3] = s3;
                }
            };
            pf(bA, 0);
            for (int c = 0; c < NCHUNK; c += 2) {
                pf(bB, c + 1);
                pinbuf(bA, (CHUNK * 3) / 4);
                cw(bA, c);
                if (c + 2 < NCHUNK) pf(bA, c + 2);
                pinbuf(bB, (CHUNK * 3) / 4);
                cw(bB, c + 1);
            }
        }
    } else if (role == 2) {
        // ---- s2 (arithmetic verbatim) ----
        float s2 = 0.f;
        float pA[CHUNK], pB[CHUNK];
        float* w2 = wbase + 2 * BT + (size_t)b * NT;
        auto pf = [&](float* P, int c) {
            #pragma unroll
            for (int i = 0; i < CHUNK; ++i) P[i] = ip[(c * CHUNK + i) * 3 + 0];
        };
        auto cw = [&](const float* P, int c) {
            float ob[CHUNK];
            #pragma unroll
            for (int i = 0; i < CHUNK; ++i) {
                const float p = P[i];
                const float e2  = ex2(-L2E10 * s2);
                const float e2p = ex2c(fmaf(-L2E10, s2, c_2p));
                const float R2  = rcpf((1.0f + e2) * (1.0f + e2p));
                const float E2  = ex2(fmaf(fE, s2, c_E2));
                const float qpref = R2 * fmaf(e2p * E2, kp * p, qpmax_);
                s2 += clip1e5(qpref);
                ob[i] = s2;
            }
            if (use_ws) plane_storeN(w2, ob, c * CHUNK, CHUNK / 4);
            else {
                #pragma unroll
                for (int i = 0; i < CHUNK; ++i) op[(c * CHUNK + i) * 5 + 2] = ob[i];
            }
        };
        pf(pA, 0);
        for (int c = 0; c < NCHUNK; c += 2) {
            pf(pB, c + 1);
            pinbuf(pA, CHUNK / 4);
            cw(pA, c);
            if (c + 2 < NCHUNK) pf(pA, c + 2);
            pinbuf(pB, CHUNK / 4);
            cw(pB, c + 1);
        }
    } else {
        // ---- s4 (arithmetic verbatim) ----
        float s4 = 0.f;
        float pA[CHUNK], pB[CHUNK];
        float* w4 = wbase + 4 * BT + (size_t)b * NT;
        auto pf = [&](float* P, int c) {
            #pragma unroll
            for (int i = 0; i < CHUNK; ++i) P[i] = ip[(c * CHUNK + i) * 3 + 0];
        };
        auto cw = [&](const float* P, int c) {
            float ob[CHUNK];
            #pragma unroll
            for (int i = 0; i < CHUNK; ++i) {
                const float p = P[i];
                const float e4  = ex2(-L2E10 * s4);
                const float e4s = ex2c(fmaf(-L2E10, s4, c_4s));
                const float R4  = rcpf((1.0f + e4) * (1.0f + e4s));
                const float E4  = ex2(fmaf(fE, s4, c_E4));
                const float pl  = p * fmaf(p, Kn_, Kl_);
                const float qslow = R4 * fmaf(e4s * E4, pl, qgmax_);
                s4 += clip1e5(qslow);
                ob[i] = s4;
            }
            if (use_ws) plane_storeN(w4, ob, c * CHUNK, CHUNK / 4);
            else {
                #pragma unroll
                for (int i = 0; i < CHUNK; ++i) op[(c * CHUNK + i) * 5 + 4] = ob[i];
            }
        };
        pf(pA, 0);
        for (int c = 0; c < NCHUNK; c += 2) {
            pf(pB, c + 1);
            pinbuf(pA, CHUNK / 4);
            cw(pA, c);
            if (c + 2 < NCHUNK) pf(pA, c + 2);
            pinbuf(pB, CHUNK / 4);
            cw(pB, c + 1);
        }
    }
}

// ---- Pass 2: SoA planes -> AoS out (verbatim) ----
__global__ __launch_bounds__(256)
void tx_kernel(const float* __restrict__ wsp, float* __restrict__ out) {
    const size_t idx = (size_t)blockIdx.x * 256 + threadIdx.x;  // BT/4 threads
    const size_t b  = idx / (NT / 4);
    const size_t t0 = (idx % (NT / 4)) * 4;
    const float* base = wsp + b * NT + t0;
    const float4 v0 = *(const float4*)(base + 0 * BT);
    const float4 v1 = *(const float4*)(base + 1 * BT);
    const float4 v2 = *(const float4*)(base + 2 * BT);
    const float4 v3 = *(const float4*)(base + 3 * BT);
    const float4 v4 = *(const float4*)(base + 4 * BT);
    float4* o = (float4*)(out + (b * NT + t0) * 5);
    o[0] = make_float4(v0.x, v1.x, v2.x, v3.x);
    o[1] = make_float4(v4.x, v0.y, v1.y, v2.y);
    o[2] = make_float4(v3.y, v4.y, v0.z, v1.z);
    o[3] = make_float4(v2.z, v3.z, v4.z, v0.w);
    o[4] = make_float4(v1.w, v2.w, v3.w, v4.w);
}

extern "C" void kernel_launch(void* const* d_in, const int* in_sizes, int n_in,
                              void* d_out, int out_size, void* d_ws, size_t ws_size,
                              hipStream_t stream) {
    const float* inp   = (const float*)d_in[0];
    const float* theta = (const float*)d_in[1];
    float* out = (float*)d_out;
    float* wsp = (float*)d_ws;
    const int use_ws = (wsp != nullptr && ws_size >= 5 * sizeof(float) * BT) ? 1 : 0;
    if (use_ws)
        pre_kernel<<<(int)(BT / 256), 256, 0, stream>>>(inp, theta, out);
    prnn_roles<<<4 * (NB / 64), 64, 0, stream>>>(inp, theta, out, wsp, use_ws);
    if (use_ws)
        tx_kernel<<<(int)(BT / 4 / 256), 256, 0, stream>>>(wsp, out);
}